// Round 5
// baseline (3139.524 us; speedup 1.0000x reference)
//
#include <hip/hip_runtime.h>
#include <math.h>

constexpr int B_   = 64;
constexpr int T_   = 512;
constexpr int D_   = 512;
constexpr int H_   = 1024;
constexpr int IMG_ = 2048;
constexpr int NWG  = 256;
constexpr int NTHR = 256;
constexpr int KTOT = D_ + H_;   // 1536
constexpr size_t SLOT_U16 = (size_t)B_ * H_;          // one publish slot (bf16 h*d)
constexpr size_t RING_BYTES = (size_t)(T_ + 1) * SLOT_U16 * 2;

typedef __attribute__((ext_vector_type(8)))  short          short8;
typedef __attribute__((ext_vector_type(16))) float          f32x16;
typedef __attribute__((ext_vector_type(4)))  unsigned       uint4v;

__device__ __forceinline__ unsigned short f2bf(float f) {
  unsigned u = __float_as_uint(f);
  u += 0x7FFFu + ((u >> 16) & 1u);     // RTNE
  return (unsigned short)(u >> 16);
}

__device__ __forceinline__ float sigf(float v) {
  return __fdividef(1.0f, 1.0f + __expf(-v));
}
__device__ __forceinline__ float tanhfast(float v) {
  v = fminf(15.0f, fmaxf(-15.0f, v));
  const float e = __expf(2.0f * v);
  return __fdividef(e - 1.0f, e + 1.0f);
}

// pack 8 f32 (two float4) -> short8 bf16 via v_cvt_pk_bf16_f32
__device__ __forceinline__ short8 pk8(const float4 a, const float4 b) {
  union { unsigned u[4]; short8 s; } r;
  asm("v_cvt_pk_bf16_f32 %0, %1, %2" : "=v"(r.u[0]) : "v"(a.x), "v"(a.y));
  asm("v_cvt_pk_bf16_f32 %0, %1, %2" : "=v"(r.u[1]) : "v"(a.z), "v"(a.w));
  asm("v_cvt_pk_bf16_f32 %0, %1, %2" : "=v"(r.u[2]) : "v"(b.x), "v"(b.y));
  asm("v_cvt_pk_bf16_f32 %0, %1, %2" : "=v"(r.u[3]) : "v"(b.z), "v"(b.w));
  return r.s;
}

// Persistent multimodal-LSTM v5.
// - RING=1: per-step unique publish slots in ws; consumers use plain CACHED
//   frag loads (L2 can never be stale: address never touched pre-flag within a
//   replay; cross-replay values bit-identical; dispatch acquire invalidates L2).
// - RING=0 fallback (small ws): 2 alternating slots + sc0sc1 bypass frag loads.
// - No Axlds: h-panel and x-tile load straight into MFMA A-fragment layout
//   (lane&31 = row, (lane>>5)*8 = k-offset), x cvt'd f32->bf16 in-register.
// - Release: publish -> __syncthreads (vmcnt0+bar) -> per-WG flag store.
template<int RING>
__global__ void __launch_bounds__(NTHR, 1)
mmlstm_persistent(const float* __restrict__ x,
                  const float* __restrict__ img,
                  const float* __restrict__ W_ih,
                  const float* __restrict__ W_hh,
                  const float* __restrict__ b_ih,
                  const float* __restrict__ b_hh,
                  const float* __restrict__ W_m,
                  float* __restrict__ out,
                  float* __restrict__ hn,
                  float* __restrict__ cn,
                  unsigned* __restrict__ flags,
                  unsigned short* __restrict__ ring)
{
  __shared__ unsigned short Wlds[32 * KTOT];   // 96 KiB, XOR-swizzled
  __shared__ float gaccs[4][32][33];
  __shared__ float bias_lds[32];

  const int tid  = threadIdx.x;
  const int lane = tid & 63;
  const int wv   = tid >> 6;
  const int wg   = blockIdx.x;
  const int rgid = wg & 1;
  const int cgid = wg >> 1;
  const int brow0 = rgid * 32;
  const int j0    = cgid * 8;

  unsigned* myflags = flags + rgid * 128;
  unsigned* myslot  = myflags + cgid;

  // ---- stage W slice (32 gate rows = 4 gates x 8 h-cols), bf16, XOR-swizzled ----
  for (int c = 0; c < 32; ++c) {
    const int grow = (c >> 3) * H_ + j0 + (c & 7);
    const int sw   = (c & 15) << 3;
    for (int k = tid; k < KTOT; k += NTHR) {
      const float w = (k < D_) ? W_ih[(size_t)grow * D_ + k]
                               : W_hh[(size_t)grow * H_ + (k - D_)];
      Wlds[c * KTOT + (k ^ sw)] = f2bf(w);
    }
  }
  if (tid < 32) {
    const int grow = (tid >> 3) * H_ + j0 + (tid & 7);
    bias_lds[tid] = b_ih[grow] + b_hh[grow];
  }

  const int b_l = tid >> 3;
  const int jj  = tid & 7;
  const int b   = brow0 + b_l;
  const int j   = j0 + jj;

  // multimodal gate d[b][j] = img[b] . W_m[j]
  float dval = 0.0f;
  {
    const float4* ir = (const float4*)(img + (size_t)b * IMG_);
    const float4* wr = (const float4*)(W_m + (size_t)j * IMG_);
    for (int k = 0; k < IMG_ / 4; ++k) {
      const float4 a = ir[k];
      const float4 w = wr[k];
      dval += a.x * w.x + a.y * w.y + a.z * w.z + a.w * w.w;
    }
  }

  // fragment coordinates (A-operand of 32x32x16: row=lane&31, k-off=(lane>>5)*8)
  const int am = lane & 31;
  const int kh = (lane >> 5) << 3;
  const int cc = lane & 31;            // B-operand gate-col
  const int csw = (cc & 15) << 3;      // Wlds swizzle for this col

  // publish h0*d = 0 into slot 0
  {
    unsigned* s0 = (unsigned*)ring;
    if ((tid & 1) == 0)
      __hip_atomic_store(s0 + (size_t)b * (H_ / 2) + (j >> 1), 0u,
                         __ATOMIC_RELAXED, __HIP_MEMORY_SCOPE_AGENT);
  }
  float  cstate = 0.0f;
  f32x16 acc    = {};

  __syncthreads();                      // vmcnt(0) + barrier: publishes drained
  if (tid == 0)
    __hip_atomic_store(myslot, 1u, __ATOMIC_RELAXED, __HIP_MEMORY_SCOPE_AGENT);

  float4 xr[16];
  auto xloadfrag = [&](int t) {        // x direct in frag layout (fp32, cached)
    const float* rb = x + ((size_t)(brow0 + am) * T_ + t) * D_;
    #pragma unroll
    for (int s8 = 0; s8 < 8; ++s8) {
      const int k = (wv + 4 * s8) * 16 + kh;
      xr[2 * s8]     = *(const float4*)(rb + k);
      xr[2 * s8 + 1] = *(const float4*)(rb + k + 4);
    }
  };

  auto poll = [&](unsigned target) {
    for (;;) {
      const unsigned a = __hip_atomic_load(myflags + lane,      __ATOMIC_RELAXED, __HIP_MEMORY_SCOPE_AGENT);
      const unsigned c = __hip_atomic_load(myflags + 64 + lane, __ATOMIC_RELAXED, __HIP_MEMORY_SCOPE_AGENT);
      if (__all(a >= target && c >= target)) break;
    }
  };

  xloadfrag(0);

  for (int t = 0; t < T_; ++t) {
    poll((unsigned)(t + 1));
    asm volatile("" ::: "memory");     // no ring loads hoist above the flag check

    // ---- h-panel A-fragments straight from the ring slot ----
    const unsigned short* sp = ring + (size_t)(RING ? t : (t & 1)) * SLOT_U16
                             + (size_t)(brow0 + am) * H_ + kh;
    short8 hfr[16];
    if (RING) {
      #pragma unroll
      for (int si = 0; si < 16; ++si)
        hfr[si] = *(const short8*)(sp + (wv + 4 * si) * 16);
    } else {
      uint4v tmp[16];
      #pragma unroll
      for (int si = 0; si < 16; ++si) {
        const unsigned short* ap = sp + (wv + 4 * si) * 16;
        asm volatile("global_load_dwordx4 %0, %1, off sc0 sc1" : "=&v"(tmp[si]) : "v"(ap));
      }
      asm volatile("s_waitcnt vmcnt(0)" ::: "memory");
      __builtin_amdgcn_sched_barrier(0);
      #pragma unroll
      for (int si = 0; si < 16; ++si)
        hfr[si] = *(short8*)&tmp[si];
    }

    // ---- x contribution: cvt in-register + 8 MFMA (h loads in flight) ----
    acc = {};
    #pragma unroll
    for (int s8 = 0; s8 < 8; ++s8) {
      const int k = (wv + 4 * s8) * 16 + kh;
      const short8 af = pk8(xr[2 * s8], xr[2 * s8 + 1]);
      const short8 bf = *(const short8*)(Wlds + cc * KTOT + (k ^ csw));
      acc = __builtin_amdgcn_mfma_f32_32x32x16_bf16(af, bf, acc, 0, 0, 0);
    }
    // ---- recurrent contribution: 16 MFMA over K=1024 ----
    #pragma unroll
    for (int si = 0; si < 16; ++si) {
      const int kglb = D_ + (wv + 4 * si) * 16 + kh;
      const short8 bf = *(const short8*)(Wlds + cc * KTOT + (kglb ^ csw));
      acc = __builtin_amdgcn_mfma_f32_32x32x16_bf16(hfr[si], bf, acc, 0, 0, 0);
    }

    // ---- per-wave partials (C/D: col=lane&31, row=(rr&3)+8*(rr>>2)+4*(lane>>5)) ----
    {
      const int colw  = lane & 31;
      const int rbase = (lane >> 5) * 4;
      #pragma unroll
      for (int rr = 0; rr < 16; ++rr) {
        const int row = (rr & 3) + 8 * (rr >> 2) + rbase;
        gaccs[wv][row][colw] = acc[rr];
      }
    }
    __syncthreads();

    // ---- cell update: thread owns (b, j) ----
    float gv[4];
    #pragma unroll
    for (int g = 0; g < 4; ++g) {
      const int c = g * 8 + jj;
      gv[g] = gaccs[0][b_l][c] + gaccs[1][b_l][c] + gaccs[2][b_l][c] + gaccs[3][b_l][c]
            + bias_lds[c];
    }
    const float ig = sigf(gv[0]);
    const float fg = sigf(gv[1]);
    const float gg = tanhfast(gv[2]);
    const float og = sigf(gv[3]);
    cstate = fg * cstate + ig * gg;
    const float h = og * tanhfast(cstate);

    // ---- publish h*d to slot t+1 (packed u32, coherent write-through) ----
    {
      unsigned* np = (unsigned*)(ring + (size_t)(RING ? (t + 1) : ((t + 1) & 1)) * SLOT_U16);
      const unsigned hd  = f2bf(h * dval);
      const unsigned nxt = __shfl_down((int)hd, 1);
      if ((jj & 1) == 0)
        __hip_atomic_store(np + (size_t)b * (H_ / 2) + (j >> 1),
                           hd | (nxt << 16),
                           __ATOMIC_RELAXED, __HIP_MEMORY_SCOPE_AGENT);
    }
    __syncthreads();                    // vmcnt(0)+barrier: all waves' publishes drained
    if (t < T_ - 1 && tid == 0)
      __hip_atomic_store(myslot, (unsigned)(t + 2), __ATOMIC_RELAXED, __HIP_MEMORY_SCOPE_AGENT);

    // off the release path:
    __builtin_nontemporal_store(h, &out[((size_t)b * T_ + t) * H_ + j]);
    if (t == T_ - 1) {
      hn[(size_t)b * H_ + j] = h;
      cn[(size_t)b * H_ + j] = cstate;
    } else {
      xloadfrag(t + 1);                 // latency overlaps next poll
    }
  }
}

extern "C" void kernel_launch(void* const* d_in, const int* in_sizes, int n_in,
                              void* d_out, int out_size, void* d_ws, size_t ws_size,
                              hipStream_t stream) {
  (void)in_sizes; (void)n_in; (void)out_size;
  const float* x    = (const float*)d_in[0];
  const float* img  = (const float*)d_in[1];
  const float* W_ih = (const float*)d_in[2];
  const float* W_hh = (const float*)d_in[3];
  const float* b_ih = (const float*)d_in[4];
  const float* b_hh = (const float*)d_in[5];
  const float* W_m  = (const float*)d_in[6];

  float* out = (float*)d_out;
  float* hn  = out + (size_t)B_ * T_ * H_;
  float* cn  = hn + (size_t)B_ * H_;

  unsigned*       flags = (unsigned*)d_ws;
  unsigned short* ring  = (unsigned short*)((char*)d_ws + 4096);

  hipMemsetAsync(d_ws, 0, 4096, stream);   // reset flag array each call

  if (ws_size >= 4096 + RING_BYTES) {
    hipLaunchKernelGGL(mmlstm_persistent<1>, dim3(NWG), dim3(NTHR), 0, stream,
                       x, img, W_ih, W_hh, b_ih, b_hh, W_m, out, hn, cn, flags, ring);
  } else {
    hipLaunchKernelGGL(mmlstm_persistent<0>, dim3(NWG), dim3(NTHR), 0, stream,
                       x, img, W_ih, W_hh, b_ih, b_hh, W_m, out, hn, cn, flags, ring);
  }
}

// Round 6
// 2045.495 us; speedup vs baseline: 1.5348x; 1.5348x over previous
//
#include <hip/hip_runtime.h>
#include <math.h>

constexpr int B_   = 64;
constexpr int T_   = 512;
constexpr int D_   = 512;
constexpr int H_   = 1024;
constexpr int IMG_ = 2048;
constexpr int NWG  = 256;
constexpr int NTHR = 256;

constexpr size_t SLOT_U16   = (size_t)B_ * H_;                 // 65536 u16 = 128 KiB
constexpr size_t RING_BYTES = (size_t)(T_ + 1) * SLOT_U16 * 2; // ~67.2 MB
constexpr size_t XBF_U16    = (size_t)B_ * T_ * D_;            // frag-major bf16 x
constexpr size_t XBF_BYTES  = XBF_U16 * 2;                     // 33.5 MB

typedef __attribute__((ext_vector_type(8)))  short          short8;
typedef __attribute__((ext_vector_type(16))) float          f32x16;
typedef __attribute__((ext_vector_type(4)))  unsigned       uint4v;

__device__ __forceinline__ unsigned short f2bf(float f) {
  unsigned u = __float_as_uint(f);
  u += 0x7FFFu + ((u >> 16) & 1u);     // RTNE
  return (unsigned short)(u >> 16);
}
__device__ __forceinline__ float sigf(float v) {
  return __fdividef(1.0f, 1.0f + __expf(-v));
}
__device__ __forceinline__ float tanhfast(float v) {
  v = fminf(15.0f, fmaxf(-15.0f, v));
  const float e = __expf(2.0f * v);
  return __fdividef(e - 1.0f, e + 1.0f);
}
// pack 8 f32 (two float4) -> short8 bf16 via v_cvt_pk_bf16_f32 (RTNE)
__device__ __forceinline__ short8 pk8(const float4 a, const float4 b) {
  union { unsigned u[4]; short8 s; } r;
  asm("v_cvt_pk_bf16_f32 %0, %1, %2" : "=v"(r.u[0]) : "v"(a.x), "v"(a.y));
  asm("v_cvt_pk_bf16_f32 %0, %1, %2" : "=v"(r.u[1]) : "v"(a.z), "v"(a.w));
  asm("v_cvt_pk_bf16_f32 %0, %1, %2" : "=v"(r.u[2]) : "v"(b.x), "v"(b.y));
  asm("v_cvt_pk_bf16_f32 %0, %1, %2" : "=v"(r.u[3]) : "v"(b.z), "v"(b.w));
  return r.s;
}

// One-time x repack: [B,T,D] f32 -> fragment-major bf16
// off_u16 = ((t*2 + half)*32 + kb)*512 + khalf*256 + row*8 + e
// where half=b>>5, row=b&31, kb=k8>>1, khalf=k8&1, e=k&7.
__global__ void __launch_bounds__(NTHR)
x_repack_kernel(const float* __restrict__ x, unsigned short* __restrict__ x_bf) {
  const int idx = blockIdx.x * NTHR + threadIdx.x;   // 2^21 chunks of 8
  const int k8 = idx & 63;
  const int t  = (idx >> 6) & 511;
  const int b  = idx >> 15;
  const float* px = x + ((size_t)b * T_ + t) * D_ + k8 * 8;
  const float4 v0 = *(const float4*)px;
  const float4 v1 = *(const float4*)(px + 4);
  const size_t off = (((size_t)t * 2 + (b >> 5)) * 32 + (k8 >> 1)) * 512
                   + (size_t)(k8 & 1) * 256 + (size_t)(b & 31) * 8;
  *(short8*)(x_bf + off) = pk8(v0, v1);
}

// Persistent multimodal-LSTM v6.
// Fragment-major ring slots: publish = 512B contiguous per WG (coherent u32
// write-through); consume = plain cached loads, 1KB contiguous per wave-instr.
// W fragments live in registers (no per-MFMA LDS). LDS only holds the
// cross-wave gate reduction (+pad to force 1 WG/CU placement).
// RING=1: per-step unique slots, plain cached consumer loads (R5-validated).
// RING=0: 2 alternating slots + sc0sc1 bypass loads. XBF=0: gather x from f32.
template<int RING, int XBF>
__global__ void __launch_bounds__(NTHR, 1)
mmlstm_persistent(const float* __restrict__ x,
                  const unsigned short* __restrict__ x_bf,
                  const float* __restrict__ img,
                  const float* __restrict__ W_ih,
                  const float* __restrict__ W_hh,
                  const float* __restrict__ b_ih,
                  const float* __restrict__ b_hh,
                  const float* __restrict__ W_m,
                  float* __restrict__ out,
                  float* __restrict__ hn,
                  float* __restrict__ cn,
                  unsigned* __restrict__ flags,
                  unsigned short* __restrict__ ring)
{
  __shared__ float gaccs[4][32][33];
  __shared__ float bias_lds[32];
  __shared__ char  ldspad[72 * 1024];   // occupancy clamp: LDS>80KB -> 1 WG/CU

  const int tid  = threadIdx.x;
  const int lane = tid & 63;
  const int wv   = tid >> 6;
  const int wg   = blockIdx.x;
  const int rgid = wg & 1;
  const int cgid = wg >> 1;
  const int brow0 = rgid * 32;
  const int j0    = cgid * 8;

  ((volatile char*)ldspad)[tid] = 0;    // keep the pad allocated

  unsigned* myflags = flags + rgid * 128;
  unsigned* myslot  = myflags + cgid;

  const int b_l = tid >> 3;
  const int jj  = tid & 7;
  const int b   = brow0 + b_l;
  const int j   = j0 + jj;

  // ---- one-time: W fragments into registers (B-operand: col=lane&31) ----
  const int cc   = lane & 31;
  const int kh8  = (lane >> 5) << 3;
  const int grow = (cc >> 3) * H_ + j0 + (cc & 7);
  short8 bfrx[8], bfrh[16];
  #pragma unroll
  for (int s8 = 0; s8 < 8; ++s8) {
    const float* p = W_ih + (size_t)grow * D_ + (wv + 4 * s8) * 16 + kh8;
    bfrx[s8] = pk8(*(const float4*)p, *(const float4*)(p + 4));
  }
  #pragma unroll
  for (int si = 0; si < 16; ++si) {
    const float* p = W_hh + (size_t)grow * H_ + (wv + 4 * si) * 16 + kh8;
    bfrh[si] = pk8(*(const float4*)p, *(const float4*)(p + 4));
  }
  if (tid < 32) {
    const int gr = (tid >> 3) * H_ + j0 + (tid & 7);
    bias_lds[tid] = b_ih[gr] + b_hh[gr];
  }

  // multimodal gate d[b][j] = img[b] . W_m[j]
  float dval = 0.0f;
  {
    const float4* ir = (const float4*)(img + (size_t)b * IMG_);
    const float4* wr = (const float4*)(W_m + (size_t)j * IMG_);
    for (int k = 0; k < IMG_ / 4; ++k) {
      const float4 a = ir[k];
      const float4 w = wr[k];
      dval += a.x * w.x + a.y * w.y + a.z * w.z + a.w * w.w;
    }
  }

  // WG's contiguous 256-u16 region inside a slot (frag-major layout):
  const size_t wgbase = (size_t)rgid * 32768 + (size_t)(cgid >> 1) * 512
                      + (size_t)(cgid & 1) * 256;

  // publish h0*d = 0 into slot 0 (coalesced u32 write-through)
  if ((tid & 1) == 0)
    __hip_atomic_store((unsigned*)(ring + wgbase) + (tid >> 1), 0u,
                       __ATOMIC_RELAXED, __HIP_MEMORY_SCOPE_AGENT);

  float  cstate = 0.0f;
  f32x16 acc    = {};

  __syncthreads();                      // vmcnt(0)+barrier: publishes drained
  if (tid == 0)
    __hip_atomic_store(myslot, 1u, __ATOMIC_RELAXED, __HIP_MEMORY_SCOPE_AGENT);

  auto poll = [&](unsigned target) {
    for (;;) {
      const unsigned a = __hip_atomic_load(myflags + lane,      __ATOMIC_RELAXED, __HIP_MEMORY_SCOPE_AGENT);
      const unsigned c = __hip_atomic_load(myflags + 64 + lane, __ATOMIC_RELAXED, __HIP_MEMORY_SCOPE_AGENT);
      if (__all(a >= target && c >= target)) break;
    }
  };

  short8 xr[8];
  auto xprefetch = [&](int t) {
    if (XBF) {   // coalesced frag-major bf16 (1KB/wave-instr)
      const unsigned short* xb = x_bf + ((size_t)t * 2 + rgid) * 16384;
      #pragma unroll
      for (int s8 = 0; s8 < 8; ++s8)
        xr[s8] = *(const short8*)(xb + ((size_t)(wv + 4 * s8) * 64 + lane) * 8);
    } else {     // fallback: f32 row-gather + pack
      const float* rb = x + ((size_t)(brow0 + cc) * T_ + t) * D_ + kh8;
      #pragma unroll
      for (int s8 = 0; s8 < 8; ++s8) {
        const float* p = rb + (wv + 4 * s8) * 16;
        xr[s8] = pk8(*(const float4*)p, *(const float4*)(p + 4));
      }
    }
  };

  xprefetch(0);

  for (int t = 0; t < T_; ++t) {
    poll((unsigned)(t + 1));
    asm volatile("" ::: "memory");      // no ring loads hoist above the flag check

    // ---- h-panel A-fragments, coalesced from frag-major slot ----
    const unsigned short* sp = ring + (size_t)(RING ? t : (t & 1)) * SLOT_U16
                             + (size_t)rgid * 32768;
    short8 hfr[16];
    if (RING) {
      #pragma unroll
      for (int si = 0; si < 16; ++si)
        hfr[si] = *(const short8*)(sp + ((size_t)(wv + 4 * si) * 64 + lane) * 8);
    } else {
      uint4v tmp[16];
      #pragma unroll
      for (int si = 0; si < 16; ++si) {
        const unsigned short* ap = sp + ((size_t)(wv + 4 * si) * 64 + lane) * 8;
        asm volatile("global_load_dwordx4 %0, %1, off sc0 sc1" : "=&v"(tmp[si]) : "v"(ap));
      }
      asm volatile("s_waitcnt vmcnt(0)" ::: "memory");
      __builtin_amdgcn_sched_barrier(0);
      #pragma unroll
      for (int si = 0; si < 16; ++si)
        hfr[si] = *(short8*)&tmp[si];
    }

    // ---- MFMAs: x part first (operands already in regs; h loads in flight) ----
    acc = {};
    #pragma unroll
    for (int s8 = 0; s8 < 8; ++s8)
      acc = __builtin_amdgcn_mfma_f32_32x32x16_bf16(xr[s8], bfrx[s8], acc, 0, 0, 0);
    #pragma unroll
    for (int si = 0; si < 16; ++si)
      acc = __builtin_amdgcn_mfma_f32_32x32x16_bf16(hfr[si], bfrh[si], acc, 0, 0, 0);

    // ---- cross-wave reduce (C/D: col=lane&31, row=(rr&3)+8*(rr>>2)+4*(lane>>5)) ----
    {
      const int colw  = lane & 31;
      const int rbase = (lane >> 5) * 4;
      #pragma unroll
      for (int rr = 0; rr < 16; ++rr) {
        const int row = (rr & 3) + 8 * (rr >> 2) + rbase;
        gaccs[wv][row][colw] = acc[rr];
      }
    }
    __syncthreads();

    // ---- cell update: thread owns (b, j) ----
    float gv[4];
    #pragma unroll
    for (int g = 0; g < 4; ++g) {
      const int c = g * 8 + jj;
      gv[g] = gaccs[0][b_l][c] + gaccs[1][b_l][c] + gaccs[2][b_l][c] + gaccs[3][b_l][c]
            + bias_lds[c];
    }
    const float ig = sigf(gv[0]);
    const float fg = sigf(gv[1]);
    const float gg = tanhfast(gv[2]);
    const float og = sigf(gv[3]);
    cstate = fg * cstate + ig * gg;
    const float h = og * tanhfast(cstate);

    // ---- publish h*d to slot t+1: contiguous 512B per WG, write-through ----
    {
      unsigned* np = (unsigned*)(ring + (size_t)(RING ? (t + 1) : ((t + 1) & 1)) * SLOT_U16
                                 + wgbase);
      const unsigned hd  = f2bf(h * dval);
      const unsigned nxt = __shfl_down((int)hd, 1);
      if ((jj & 1) == 0)
        __hip_atomic_store(np + (tid >> 1), hd | (nxt << 16),
                           __ATOMIC_RELAXED, __HIP_MEMORY_SCOPE_AGENT);
    }
    __syncthreads();                    // vmcnt(0)+barrier: all publishes drained
    if (t < T_ - 1 && tid == 0)
      __hip_atomic_store(myslot, (unsigned)(t + 2), __ATOMIC_RELAXED, __HIP_MEMORY_SCOPE_AGENT);

    // off the release path:
    __builtin_nontemporal_store(h, &out[((size_t)b * T_ + t) * H_ + j]);
    if (t == T_ - 1) {
      hn[(size_t)b * H_ + j] = h;
      cn[(size_t)b * H_ + j] = cstate;
    } else {
      xprefetch(t + 1);                 // overlaps next poll
    }
  }
}

extern "C" void kernel_launch(void* const* d_in, const int* in_sizes, int n_in,
                              void* d_out, int out_size, void* d_ws, size_t ws_size,
                              hipStream_t stream) {
  (void)in_sizes; (void)n_in; (void)out_size;
  const float* x    = (const float*)d_in[0];
  const float* img  = (const float*)d_in[1];
  const float* W_ih = (const float*)d_in[2];
  const float* W_hh = (const float*)d_in[3];
  const float* b_ih = (const float*)d_in[4];
  const float* b_hh = (const float*)d_in[5];
  const float* W_m  = (const float*)d_in[6];

  float* out = (float*)d_out;
  float* hn  = out + (size_t)B_ * T_ * H_;
  float* cn  = hn + (size_t)B_ * H_;

  unsigned*       flags = (unsigned*)d_ws;
  unsigned short* ring  = (unsigned short*)((char*)d_ws + 4096);
  unsigned short* x_bf  = (unsigned short*)((char*)d_ws + 4096 + RING_BYTES);

  hipMemsetAsync(d_ws, 0, 4096, stream);   // reset flag array each call

  if (ws_size >= 4096 + RING_BYTES + XBF_BYTES) {
    hipLaunchKernelGGL(x_repack_kernel, dim3((B_ * T_ * D_ / 8) / NTHR), dim3(NTHR), 0, stream,
                       x, x_bf);
    hipLaunchKernelGGL((mmlstm_persistent<1, 1>), dim3(NWG), dim3(NTHR), 0, stream,
                       x, x_bf, img, W_ih, W_hh, b_ih, b_hh, W_m, out, hn, cn, flags, ring);
  } else if (ws_size >= 4096 + RING_BYTES) {
    hipLaunchKernelGGL((mmlstm_persistent<1, 0>), dim3(NWG), dim3(NTHR), 0, stream,
                       x, x_bf, img, W_ih, W_hh, b_ih, b_hh, W_m, out, hn, cn, flags, ring);
  } else {
    hipLaunchKernelGGL((mmlstm_persistent<0, 0>), dim3(NWG), dim3(NTHR), 0, stream,
                       x, x_bf, img, W_ih, W_hh, b_ih, b_hh, W_m, out, hn, cn, flags, ring);
  }
}

// Round 9
// 1542.591 us; speedup vs baseline: 2.0352x; 1.3260x over previous
//
#include <hip/hip_runtime.h>
#include <math.h>

constexpr int B_   = 64;
constexpr int T_   = 512;
constexpr int D_   = 512;
constexpr int H_   = 1024;
constexpr int IMG_ = 2048;
constexpr int NWG  = 256;
constexpr int NTHR = 256;

constexpr size_t SLOT_U16   = (size_t)B_ * H_;                 // 65536 u16 = 128 KiB
constexpr size_t RING_BYTES = (size_t)(T_ + 1) * SLOT_U16 * 2; // ~67.2 MB
constexpr size_t XBF_BYTES  = (size_t)B_ * T_ * D_ * 2;        // 33.5 MB

typedef __attribute__((ext_vector_type(8))) short    short8;
typedef __attribute__((ext_vector_type(4))) float    f32x4;
typedef __attribute__((ext_vector_type(4))) unsigned uint4v;

__device__ __forceinline__ unsigned short f2bf(float f) {
  unsigned u = __float_as_uint(f);
  u += 0x7FFFu + ((u >> 16) & 1u);     // RTNE
  return (unsigned short)(u >> 16);
}
__device__ __forceinline__ float sigf(float v) {
  return __fdividef(1.0f, 1.0f + __expf(-v));
}
__device__ __forceinline__ float tanhfast(float v) {
  v = fminf(15.0f, fmaxf(-15.0f, v));
  const float e = __expf(2.0f * v);
  return __fdividef(e - 1.0f, e + 1.0f);
}
// pack 8 f32 (two float4) -> short8 bf16 via v_cvt_pk_bf16_f32 (RTNE)
__device__ __forceinline__ short8 pk8(const float4 a, const float4 b) {
  union { unsigned u[4]; short8 s; } r;
  asm("v_cvt_pk_bf16_f32 %0, %1, %2" : "=v"(r.u[0]) : "v"(a.x), "v"(a.y));
  asm("v_cvt_pk_bf16_f32 %0, %1, %2" : "=v"(r.u[1]) : "v"(a.z), "v"(a.w));
  asm("v_cvt_pk_bf16_f32 %0, %1, %2" : "=v"(r.u[2]) : "v"(b.x), "v"(b.y));
  asm("v_cvt_pk_bf16_f32 %0, %1, %2" : "=v"(r.u[3]) : "v"(b.z), "v"(b.w));
  return r.s;
}

// One-time x repack: [B,T,D] f32 -> quarter fragment-major bf16.
// u16 off = ((t*4 + b/16)*16 + k/32)*512 + ((k/8)&3)*128 + (b&15)*8 + (k&7)
// => per-(t,quarter) block = 16 slices * 512 = 8192 u16.
__global__ void __launch_bounds__(NTHR)
x_repack_kernel(const float* __restrict__ x, unsigned short* __restrict__ x_bf) {
  const int idx = blockIdx.x * NTHR + threadIdx.x;   // 2^21 chunks of 8
  const int k8 = idx & 63;
  const int t  = (idx >> 6) & 511;
  const int b  = idx >> 15;
  const float* px = x + ((size_t)b * T_ + t) * D_ + k8 * 8;
  const float4 v0 = *(const float4*)px;
  const float4 v1 = *(const float4*)(px + 4);
  const size_t off = ((size_t)(t * 4 + (b >> 4)) * 16 + (k8 >> 2)) * 512
                   + (size_t)(k8 & 3) * 128 + (size_t)(b & 15) * 8;
  *(short8*)(x_bf + off) = pk8(v0, v1);
}

// Persistent multimodal-LSTM v8 (= v7 with the x-tile stride bug fixed:
// per-(t,q) x block is 8192 u16, NOT 16384).
// 4 independent quarters (16 batch rows); 64 WGs/quarter, 16 h-cols/WG.
// mfma_f32_16x16x32_bf16; A: row=lane&15, k-oct=lane>>4; C/D: col=lane&15,
// row=(lane>>4)*4+rr. 4 independent acc chains (4 gate tiles).
// Coherence (validated R2-R6): publish = relaxed agent u32 write-through;
// consume = plain cached loads (fresh addresses within dispatch; dispatch
// acquire invalidates L2); release = __syncthreads -> per-WG flag;
// poll = 1 flag/lane.
template<int RING, int XBF>
__global__ void __launch_bounds__(NTHR, 1)
mmlstm_persistent(const float* __restrict__ x,
                  const unsigned short* __restrict__ x_bf,
                  const float* __restrict__ img,
                  const float* __restrict__ W_ih,
                  const float* __restrict__ W_hh,
                  const float* __restrict__ b_ih,
                  const float* __restrict__ b_hh,
                  const float* __restrict__ W_m,
                  float* __restrict__ out,
                  float* __restrict__ hn,
                  float* __restrict__ cn,
                  unsigned* __restrict__ flags,
                  unsigned short* __restrict__ ring)
{
  __shared__ float gaccs[4][16][68];    // [wave][brow][gatecol] ~17.4 KiB
  __shared__ float bias_lds[64];
  __shared__ char  ldspad[72 * 1024];   // force 1 WG/CU placement

  const int tid  = threadIdx.x;
  const int lane = tid & 63;
  const int wv   = tid >> 6;
  const int wg   = blockIdx.x;
  const int q    = wg & 3;              // quarter
  const int cgid = wg >> 2;             // 0..63 within quarter
  const int b0   = q * 16;
  const int j0   = cgid * 16;

  ((volatile char*)ldspad)[tid] = 0;

  unsigned* myflags = flags + q * 64;
  unsigned* myslot  = myflags + cgid;

  // ---- one-time: W fragments into registers ----
  // B-frag (16x16x32): col=lane&15, k-octet=lane>>4. tile = gate g.
  const int cloc = lane & 15;
  const int ko8  = (lane >> 4) << 3;
  short8 wx[4][4], wh[4][8];
  #pragma unroll
  for (int tile = 0; tile < 4; ++tile) {
    const int grow = tile * H_ + j0 + cloc;
    #pragma unroll
    for (int sx = 0; sx < 4; ++sx) {
      const float* p = W_ih + (size_t)grow * D_ + (wv + 4 * sx) * 32 + ko8;
      wx[tile][sx] = pk8(*(const float4*)p, *(const float4*)(p + 4));
    }
    #pragma unroll
    for (int sh = 0; sh < 8; ++sh) {
      const float* p = W_hh + (size_t)grow * H_ + (wv + 4 * sh) * 32 + ko8;
      wh[tile][sh] = pk8(*(const float4*)p, *(const float4*)(p + 4));
    }
  }
  if (tid < 64) {
    const int grow = (tid >> 4) * H_ + j0 + (tid & 15);
    bias_lds[tid] = b_ih[grow] + b_hh[grow];
  }

  // ---- per-thread ownership: thread = (b_l, jj), 1 h value ----
  const int b_l = tid >> 4;             // 0..15 batch row in quarter
  const int jj  = tid & 15;             // 0..15 h-col in WG
  const int b   = b0 + b_l;
  const int j   = j0 + jj;

  // publish offset (u16, within quarter-slot) for (b_l, j)
  const int poff = (j >> 5) * 512 + ((j >> 3) & 3) * 128 + b_l * 8 + (j & 7);

  // multimodal gate d[b][j] = img[b] . W_m[j]
  float dval = 0.0f;
  {
    const float4* ir = (const float4*)(img + (size_t)b * IMG_);
    const float4* wr = (const float4*)(W_m + (size_t)j * IMG_);
    for (int k = 0; k < IMG_ / 4; ++k) {
      const float4 a = ir[k];
      const float4 w = wr[k];
      dval += a.x * w.x + a.y * w.y + a.z * w.z + a.w * w.w;
    }
  }

  // publish h0*d = 0 into slot 0 (coalesced u32 write-through)
  if ((jj & 1) == 0)
    __hip_atomic_store((unsigned*)(ring + (size_t)q * 16384 + poff), 0u,
                       __ATOMIC_RELAXED, __HIP_MEMORY_SCOPE_AGENT);

  float cstate = 0.0f;

  __syncthreads();                      // vmcnt(0)+barrier: publishes drained
  if (tid == 0)
    __hip_atomic_store(myslot, 1u, __ATOMIC_RELAXED, __HIP_MEMORY_SCOPE_AGENT);

  auto poll = [&](unsigned target) {    // exactly 1 flag per lane
    for (;;) {
      const unsigned f = __hip_atomic_load(myflags + lane, __ATOMIC_RELAXED,
                                           __HIP_MEMORY_SCOPE_AGENT);
      if (__all(f >= target)) break;
    }
  };

  short8 xr[4];
  auto xprefetch = [&](int t) {
    if (XBF) {   // coalesced quarter-frag-major bf16 (1KB/wave-instr)
      const unsigned short* xb = x_bf + ((size_t)t * 4 + q) * 8192;   // FIXED stride
      #pragma unroll
      for (int sx = 0; sx < 4; ++sx)
        xr[sx] = *(const short8*)(xb + (size_t)(wv + 4 * sx) * 512 + lane * 8);
    } else {     // fallback: f32 row-gather + pack
      const float* rb = x + ((size_t)(b0 + cloc) * T_ + t) * D_ + ko8;
      #pragma unroll
      for (int sx = 0; sx < 4; ++sx) {
        const float* p = rb + (wv + 4 * sx) * 32;
        xr[sx] = pk8(*(const float4*)p, *(const float4*)(p + 4));
      }
    }
  };

  xprefetch(0);

  for (int t = 0; t < T_; ++t) {
    poll((unsigned)(t + 1));
    asm volatile("" ::: "memory");      // no ring loads hoist above the flag check

    // ---- h-panel A-fragments: 8 coalesced loads (32 KB/WG total) ----
    const unsigned short* sp = ring + (size_t)(RING ? t : (t & 1)) * SLOT_U16
                             + (size_t)q * 16384;
    short8 hfr[8];
    if (RING) {
      #pragma unroll
      for (int sh = 0; sh < 8; ++sh)
        hfr[sh] = *(const short8*)(sp + (size_t)(wv + 4 * sh) * 512 + lane * 8);
    } else {
      uint4v tmp[8];
      #pragma unroll
      for (int sh = 0; sh < 8; ++sh) {
        const unsigned short* ap = sp + (size_t)(wv + 4 * sh) * 512 + lane * 8;
        asm volatile("global_load_dwordx4 %0, %1, off sc0 sc1" : "=&v"(tmp[sh]) : "v"(ap));
      }
      asm volatile("s_waitcnt vmcnt(0)" ::: "memory");
      __builtin_amdgcn_sched_barrier(0);
      #pragma unroll
      for (int sh = 0; sh < 8; ++sh)
        hfr[sh] = *(short8*)&tmp[sh];
    }

    // ---- MFMAs: 4 independent acc chains (one per gate tile) ----
    f32x4 ac[4];
    #pragma unroll
    for (int tile = 0; tile < 4; ++tile) ac[tile] = (f32x4){0.f, 0.f, 0.f, 0.f};
    #pragma unroll
    for (int sx = 0; sx < 4; ++sx) {
      #pragma unroll
      for (int tile = 0; tile < 4; ++tile)
        ac[tile] = __builtin_amdgcn_mfma_f32_16x16x32_bf16(xr[sx], wx[tile][sx], ac[tile], 0, 0, 0);
    }
    #pragma unroll
    for (int sh = 0; sh < 8; ++sh) {
      #pragma unroll
      for (int tile = 0; tile < 4; ++tile)
        ac[tile] = __builtin_amdgcn_mfma_f32_16x16x32_bf16(hfr[sh], wh[tile][sh], ac[tile], 0, 0, 0);
    }

    // ---- cross-wave reduce (C/D: col=lane&15, row=(lane>>4)*4+rr) ----
    {
      const int crow = (lane >> 4) * 4;
      #pragma unroll
      for (int tile = 0; tile < 4; ++tile) {
        #pragma unroll
        for (int rr = 0; rr < 4; ++rr)
          gaccs[wv][crow + rr][tile * 16 + cloc] = ac[tile][rr];
      }
    }
    __syncthreads();

    // ---- cell update: thread owns (b, j) ----
    float gv[4];
    #pragma unroll
    for (int g = 0; g < 4; ++g) {
      const int c = g * 16 + jj;
      gv[g] = gaccs[0][b_l][c] + gaccs[1][b_l][c] + gaccs[2][b_l][c] + gaccs[3][b_l][c]
            + bias_lds[c];
    }
    const float ig = sigf(gv[0]);
    const float fg = sigf(gv[1]);
    const float gg = tanhfast(gv[2]);
    const float og = sigf(gv[3]);
    cstate = fg * cstate + ig * gg;
    const float h = og * tanhfast(cstate);

    // ---- publish h*d to slot t+1 (1 coalesced u32 per even thread) ----
    {
      const unsigned hd  = f2bf(h * dval);
      const unsigned nxt = __shfl_down((int)hd, 1);
      if ((jj & 1) == 0)
        __hip_atomic_store((unsigned*)(ring + (size_t)(RING ? (t + 1) : ((t + 1) & 1)) * SLOT_U16
                                       + (size_t)q * 16384 + poff),
                           hd | (nxt << 16),
                           __ATOMIC_RELAXED, __HIP_MEMORY_SCOPE_AGENT);
    }
    __syncthreads();                    // vmcnt(0)+barrier: all publishes drained
    if (t < T_ - 1 && tid == 0)
      __hip_atomic_store(myslot, (unsigned)(t + 2), __ATOMIC_RELAXED, __HIP_MEMORY_SCOPE_AGENT);

    // off the release path:
    __builtin_nontemporal_store(h, &out[((size_t)b * T_ + t) * H_ + j]);
    if (t == T_ - 1) {
      hn[(size_t)b * H_ + j] = h;
      cn[(size_t)b * H_ + j] = cstate;
    } else {
      xprefetch(t + 1);                 // overlaps next poll
    }
  }
}

extern "C" void kernel_launch(void* const* d_in, const int* in_sizes, int n_in,
                              void* d_out, int out_size, void* d_ws, size_t ws_size,
                              hipStream_t stream) {
  (void)in_sizes; (void)n_in; (void)out_size;
  const float* x    = (const float*)d_in[0];
  const float* img  = (const float*)d_in[1];
  const float* W_ih = (const float*)d_in[2];
  const float* W_hh = (const float*)d_in[3];
  const float* b_ih = (const float*)d_in[4];
  const float* b_hh = (const float*)d_in[5];
  const float* W_m  = (const float*)d_in[6];

  float* out = (float*)d_out;
  float* hn  = out + (size_t)B_ * T_ * H_;
  float* cn  = hn + (size_t)B_ * H_;

  unsigned*       flags = (unsigned*)d_ws;
  unsigned short* ring  = (unsigned short*)((char*)d_ws + 4096);
  unsigned short* x_bf  = (unsigned short*)((char*)d_ws + 4096 + RING_BYTES);

  hipMemsetAsync(d_ws, 0, 4096, stream);   // reset flag array each call

  if (ws_size >= 4096 + RING_BYTES + XBF_BYTES) {
    hipLaunchKernelGGL(x_repack_kernel, dim3((B_ * T_ * D_ / 8) / NTHR), dim3(NTHR), 0, stream,
                       x, x_bf);
    hipLaunchKernelGGL((mmlstm_persistent<1, 1>), dim3(NWG), dim3(NTHR), 0, stream,
                       x, x_bf, img, W_ih, W_hh, b_ih, b_hh, W_m, out, hn, cn, flags, ring);
  } else if (ws_size >= 4096 + RING_BYTES) {
    hipLaunchKernelGGL((mmlstm_persistent<1, 0>), dim3(NWG), dim3(NTHR), 0, stream,
                       x, x_bf, img, W_ih, W_hh, b_ih, b_hh, W_m, out, hn, cn, flags, ring);
  } else {
    hipLaunchKernelGGL((mmlstm_persistent<0, 0>), dim3(NWG), dim3(NTHR), 0, stream,
                       x, x_bf, img, W_ih, W_hh, b_ih, b_hh, W_m, out, hn, cn, flags, ring);
  }
}